// Round 1
// baseline (636.472 us; speedup 1.0000x reference)
//
#include <hip/hip_runtime.h>
#include <hip/hip_bf16.h>

#define S_LEN 1024
#define DM 1024
#define NH 16
#define DH 64
#define BB 4

typedef short s16x8 __attribute__((ext_vector_type(8)));
typedef short s16x4 __attribute__((ext_vector_type(4)));
typedef float f32x4 __attribute__((ext_vector_type(4)));

__device__ __forceinline__ unsigned short f2b(float f) {
    __hip_bfloat16 h = __float2bfloat16(f);
    return __builtin_bit_cast(unsigned short, h);
}

// ---------------- convert fp32 -> bf16 for x, Wq, Wk, Wv, Wo ----------------
__global__ void convert_all(const float* __restrict__ x, const float* __restrict__ wq,
                            const float* __restrict__ wk, const float* __restrict__ wv,
                            const float* __restrict__ wo,
                            unsigned short* __restrict__ xb, unsigned short* __restrict__ wqb,
                            unsigned short* __restrict__ wkb, unsigned short* __restrict__ wvb,
                            unsigned short* __restrict__ wob) {
    const int tid = blockIdx.x * blockDim.x + threadIdx.x;
    const int stride = gridDim.x * blockDim.x;
    auto conv = [&](const float* src, unsigned short* dst, int n4) {
        const float4* s4 = (const float4*)src;
        s16x4* d4 = (s16x4*)dst;
        for (int i = tid; i < n4; i += stride) {
            float4 f = s4[i];
            s16x4 o = { (short)f2b(f.x), (short)f2b(f.y), (short)f2b(f.z), (short)f2b(f.w) };
            d4[i] = o;
        }
    };
    conv(x,  xb,  (BB * S_LEN * DM) / 4);
    conv(wq, wqb, (DM * DM) / 4);
    conv(wk, wkb, (DH * DM) / 4);
    conv(wv, wvb, (DH * DM) / 4);
    conv(wo, wob, (DM * DM) / 4);
}

// ---------------- GEMM: out[m,n] = sum_k A[m,k] * Bw[n,k]  (both row-major, bf16) --------
// MODE 0: write bf16 out (q). MODE 1: split epilogue -> k row-major + v transposed.
// MODE 2: fp32 out + bias (final projection).
template <int MODE>
__global__ __launch_bounds__(256) void gemm_bt(
    const unsigned short* __restrict__ A, const unsigned short* __restrict__ Bw,
    int M, int N, int K,
    unsigned short* __restrict__ outb,
    unsigned short* __restrict__ koutb, unsigned short* __restrict__ vtout,
    float* __restrict__ outf, const float* __restrict__ bias) {
    __shared__ unsigned short As[128 * 72];  // rows padded 64 -> 72 to break bank conflicts
    __shared__ unsigned short Bs[128 * 72];
    const int t = threadIdx.x;
    const int w = t >> 6, lane = t & 63, qd = lane >> 4, c = lane & 15;
    const int m0 = blockIdx.x * 128, n0 = blockIdx.y * 128;
    const int wm = (w >> 1) * 64, wn = (w & 1) * 64;

    f32x4 acc[4][4];
    for (int mb = 0; mb < 4; ++mb)
        for (int nb = 0; nb < 4; ++nb) acc[mb][nb] = (f32x4){0.f, 0.f, 0.f, 0.f};

    for (int kk = 0; kk < K; kk += 64) {
        __syncthreads();
#pragma unroll
        for (int it = 0; it < 4; ++it) {
            int vi = it * 256 + t;
            int row = vi >> 3, col8 = (vi & 7) * 8;
            *(s16x8*)&As[row * 72 + col8] = *(const s16x8*)&A[(size_t)(m0 + row) * K + kk + col8];
            *(s16x8*)&Bs[row * 72 + col8] = *(const s16x8*)&Bw[(size_t)(n0 + row) * K + kk + col8];
        }
        __syncthreads();
#pragma unroll
        for (int kb = 0; kb < 2; ++kb) {
            s16x8 af[4], bf[4];
#pragma unroll
            for (int mb = 0; mb < 4; ++mb)
                af[mb] = *(const s16x8*)&As[(wm + mb * 16 + c) * 72 + kb * 32 + qd * 8];
#pragma unroll
            for (int nb = 0; nb < 4; ++nb)
                bf[nb] = *(const s16x8*)&Bs[(wn + nb * 16 + c) * 72 + kb * 32 + qd * 8];
#pragma unroll
            for (int mb = 0; mb < 4; ++mb)
#pragma unroll
                for (int nb = 0; nb < 4; ++nb)
                    acc[mb][nb] = __builtin_amdgcn_mfma_f32_16x16x32_bf16(af[mb], bf[nb], acc[mb][nb], 0, 0, 0);
        }
    }

#pragma unroll
    for (int mb = 0; mb < 4; ++mb)
#pragma unroll
        for (int nb = 0; nb < 4; ++nb)
#pragma unroll
            for (int r = 0; r < 4; ++r) {
                int row = m0 + wm + mb * 16 + qd * 4 + r;
                int col = n0 + wn + nb * 16 + c;
                float v = acc[mb][nb][r];
                if (MODE == 0) {
                    outb[(size_t)row * N + col] = f2b(v);
                } else if (MODE == 2) {
                    outf[(size_t)row * N + col] = v + bias[col];
                } else {
                    if (col < 64)
                        koutb[(size_t)row * 64 + col] = f2b(v);
                    else
                        vtout[(size_t)(row >> 10) * 65536 + (size_t)(col - 64) * 1024 + (row & 1023)] = f2b(v);
                }
            }
}

// ---------------- fused attention: one workgroup per query position i -------------
// wave w handles batch b = w (16 heads -> one 16-row MFMA block).
// score[h, j] = q . (k_b[j]) + q . rel[i,j]; both MFMAs accumulate into same C.
__global__ __launch_bounds__(256) void attn_kernel(
    const unsigned short* __restrict__ qb, const unsigned short* __restrict__ kg,
    const unsigned short* __restrict__ vt, const float* __restrict__ rel,
    unsigned short* __restrict__ ctx) {
    __shared__ unsigned short rel_s[128 * 72];   // bf16 rel tile [128 j][64 d], padded
    __shared__ unsigned short P_s[4 * 16 * 136]; // per-wave P tile [16 h][128 j], padded
    const int i = blockIdx.x;
    const int t = threadIdx.x;
    const int w = t >> 6, lane = t & 63, qd = lane >> 4, c = lane & 15;
    const int b = w;

    // Q A-fragments: A[m=c(head)][k=qd*8+idx (+32*kb)]
    s16x8 aq[2];
    {
        const size_t qbase = ((size_t)(b * S_LEN + i)) * DM + (size_t)c * DH + qd * 8;
        aq[0] = *(const s16x8*)&qb[qbase];
        aq[1] = *(const s16x8*)&qb[qbase + 32];
    }

    f32x4 oacc[4];
    for (int nb = 0; nb < 4; ++nb) oacc[nb] = (f32x4){0.f, 0.f, 0.f, 0.f};
    float m_run[4], l_run[4];
    for (int r = 0; r < 4; ++r) { m_run[r] = -INFINITY; l_run[r] = 0.f; }

    const float C2 = 0.125f * 1.44269504088896f;  // scale * log2(e)

    for (int jt = 0; jt < 8; ++jt) {
        const int j0 = jt * 128;
        __syncthreads();
        // cooperative stage rel[i, j0:j0+128, 0:64] fp32 -> bf16 LDS
        {
            const size_t base = ((size_t)i * S_LEN + j0) * DH;
#pragma unroll
            for (int it = 0; it < 8; ++it) {
                int vi = it * 256 + t;
                int row = vi >> 4, d4 = (vi & 15) * 4;
                float4 f = *(const float4*)&rel[base + (size_t)row * 64 + d4];
                s16x4 o = { (short)f2b(f.x), (short)f2b(f.y), (short)f2b(f.z), (short)f2b(f.w) };
                *(s16x4*)&rel_s[row * 72 + d4] = o;
            }
        }
        __syncthreads();

        // scores: [16 h, 128 j] = Q (16x64) @ (K_b + rel_i)^T via two accumulating MFMAs
        f32x4 sa[8];
#pragma unroll
        for (int jb = 0; jb < 8; ++jb) sa[jb] = (f32x4){0.f, 0.f, 0.f, 0.f};
#pragma unroll
        for (int kb = 0; kb < 2; ++kb) {
#pragma unroll
            for (int jb = 0; jb < 8; ++jb) {
                s16x8 rf = *(const s16x8*)&rel_s[(jb * 16 + c) * 72 + kb * 32 + qd * 8];
                sa[jb] = __builtin_amdgcn_mfma_f32_16x16x32_bf16(aq[kb], rf, sa[jb], 0, 0, 0);
                s16x8 kf = *(const s16x8*)&kg[((size_t)b * S_LEN + j0 + jb * 16 + c) * DH + kb * 32 + qd * 8];
                sa[jb] = __builtin_amdgcn_mfma_f32_16x16x32_bf16(aq[kb], kf, sa[jb], 0, 0, 0);
            }
        }

        // online softmax (base-2). C-layout: row h = qd*4 + r, col j = jb*16 + c.
        float alpha[4];
#pragma unroll
        for (int r = 0; r < 4; ++r) {
            float mx = -INFINITY;
#pragma unroll
            for (int jb = 0; jb < 8; ++jb) {
                sa[jb][r] *= C2;
                mx = fmaxf(mx, sa[jb][r]);
            }
            mx = fmaxf(mx, __shfl_xor(mx, 1));
            mx = fmaxf(mx, __shfl_xor(mx, 2));
            mx = fmaxf(mx, __shfl_xor(mx, 4));
            mx = fmaxf(mx, __shfl_xor(mx, 8));
            float mnew = fmaxf(m_run[r], mx);
            alpha[r] = exp2f(m_run[r] - mnew);
            m_run[r] = mnew;
            float s = 0.f;
#pragma unroll
            for (int jb = 0; jb < 8; ++jb) {
                float p = exp2f(sa[jb][r] - mnew);
                s += p;
                P_s[(w * 16 + qd * 4 + r) * 136 + jb * 16 + c] = f2b(p);
            }
            s += __shfl_xor(s, 1);
            s += __shfl_xor(s, 2);
            s += __shfl_xor(s, 4);
            s += __shfl_xor(s, 8);
            l_run[r] = l_run[r] * alpha[r] + s;
        }
#pragma unroll
        for (int nb = 0; nb < 4; ++nb)
#pragma unroll
            for (int r = 0; r < 4; ++r) oacc[nb][r] *= alpha[r];

        __syncthreads();  // P_s writes visible before A-layout reads

        // PV: ctx[16 h, 64 d] += P[16,128] @ V[128,64]; V from transposed v_t[b][d][j]
#pragma unroll
        for (int kk2 = 0; kk2 < 4; ++kk2) {
            s16x8 pf = *(const s16x8*)&P_s[(w * 16 + c) * 136 + kk2 * 32 + qd * 8];
#pragma unroll
            for (int nb = 0; nb < 4; ++nb) {
                s16x8 vf = *(const s16x8*)&vt[(size_t)b * 65536 + (size_t)(nb * 16 + c) * 1024 + j0 + kk2 * 32 + qd * 8];
                oacc[nb] = __builtin_amdgcn_mfma_f32_16x16x32_bf16(pf, vf, oacc[nb], 0, 0, 0);
            }
        }
    }

    // epilogue: ctx[b, i, h*64 + d] = oacc / l
#pragma unroll
    for (int nb = 0; nb < 4; ++nb)
#pragma unroll
        for (int r = 0; r < 4; ++r) {
            float o = oacc[nb][r] / l_run[r];
            int h = qd * 4 + r, d = nb * 16 + c;
            ctx[((size_t)b * S_LEN + i) * DM + h * DH + d] = f2b(o);
        }
}

extern "C" void kernel_launch(void* const* d_in, const int* in_sizes, int n_in,
                              void* d_out, int out_size, void* d_ws, size_t ws_size,
                              hipStream_t stream) {
    (void)in_sizes; (void)n_in; (void)out_size; (void)ws_size;
    const float* x   = (const float*)d_in[0];
    const float* rel = (const float*)d_in[1];
    const float* Wq  = (const float*)d_in[2];
    const float* Wk  = (const float*)d_in[3];
    const float* Wv  = (const float*)d_in[4];
    const float* Wo  = (const float*)d_in[5];
    const float* bo  = (const float*)d_in[6];
    float* out = (float*)d_out;

    unsigned short* ws  = (unsigned short*)d_ws;
    unsigned short* xb  = ws;             // 4096x1024
    unsigned short* wqb = xb + 4194304;   // 1024x1024
    unsigned short* wkb = wqb + 1048576;  // 64x1024
    unsigned short* wvb = wkb + 65536;    // 64x1024 (contiguous after wkb -> one [128,1024] B)
    unsigned short* wob = wvb + 65536;    // 1024x1024
    unsigned short* qbf = wob + 1048576;  // 4096x1024 bf16 q
    unsigned short* kbf = qbf + 4194304;  // [4][1024][64] bf16 k
    unsigned short* vtb = kbf + 262144;   // [4][64][1024] bf16 v^T
    unsigned short* ctxb = vtb + 262144;  // 4096x1024 bf16 context

    convert_all<<<1024, 256, 0, stream>>>(x, Wq, Wk, Wv, Wo, xb, wqb, wkb, wvb, wob);
    gemm_bt<0><<<dim3(32, 8), 256, 0, stream>>>(xb, wqb, 4096, 1024, 1024,
                                                qbf, nullptr, nullptr, nullptr, nullptr);
    gemm_bt<1><<<dim3(32, 1), 256, 0, stream>>>(xb, wkb, 4096, 128, 1024,
                                                nullptr, kbf, vtb, nullptr, nullptr);
    attn_kernel<<<1024, 256, 0, stream>>>(qbf, kbf, vtb, rel, ctxb);
    gemm_bt<2><<<dim3(32, 8), 256, 0, stream>>>(ctxb, wob, 4096, 1024, 1024,
                                                nullptr, nullptr, nullptr, out, bo);
}

// Round 2
// 534.385 us; speedup vs baseline: 1.1910x; 1.1910x over previous
//
#include <hip/hip_runtime.h>
#include <hip/hip_bf16.h>

#define S_LEN 1024
#define DM 1024
#define NH 16
#define DH 64
#define BB 4

typedef short s16x8 __attribute__((ext_vector_type(8)));
typedef short s16x4 __attribute__((ext_vector_type(4)));
typedef float f32x4 __attribute__((ext_vector_type(4)));

__device__ __forceinline__ unsigned short f2b(float f) {
    __hip_bfloat16 h = __float2bfloat16(f);
    return __builtin_bit_cast(unsigned short, h);
}
__device__ __forceinline__ float b2f(unsigned short u) {
    unsigned int v = ((unsigned int)u) << 16;
    return __builtin_bit_cast(float, v);
}
__device__ __forceinline__ void gld16(const unsigned short* g, unsigned short* l) {
    __builtin_amdgcn_global_load_lds(
        (const __attribute__((address_space(1))) unsigned int*)g,
        (__attribute__((address_space(3))) unsigned int*)l, 16, 0, 0);
}

// ---------------- convert fp32 -> bf16 for x, Wq, Wk, Wv, Wo ----------------
__global__ void convert_all(const float* __restrict__ x, const float* __restrict__ wq,
                            const float* __restrict__ wk, const float* __restrict__ wv,
                            const float* __restrict__ wo,
                            unsigned short* __restrict__ xb, unsigned short* __restrict__ wqb,
                            unsigned short* __restrict__ wkb, unsigned short* __restrict__ wvb,
                            unsigned short* __restrict__ wob) {
    const int tid = blockIdx.x * blockDim.x + threadIdx.x;
    const int stride = gridDim.x * blockDim.x;
    auto conv = [&](const float* src, unsigned short* dst, int n4) {
        const float4* s4 = (const float4*)src;
        s16x4* d4 = (s16x4*)dst;
        for (int i = tid; i < n4; i += stride) {
            float4 f = s4[i];
            s16x4 o = { (short)f2b(f.x), (short)f2b(f.y), (short)f2b(f.z), (short)f2b(f.w) };
            d4[i] = o;
        }
    };
    conv(x,  xb,  (BB * S_LEN * DM) / 4);
    conv(wq, wqb, (DM * DM) / 4);
    conv(wk, wkb, (DH * DM) / 4);
    conv(wv, wvb, (DH * DM) / 4);
    conv(wo, wob, (DM * DM) / 4);
}

// ---------------- GEMM: out[m,n] = sum_k A[m,k] * Bw[n,k]  (row-major bf16) --------
// Tile 128(M) x 64(N), K-chunk 64, global_load_lds staging (m97 structure).
// MODE 0: fused qkv epilogue (col<1024 q, <1088 k, else v^T). MODE 2: fp32 + bias.
template <int MODE>
__global__ __launch_bounds__(256) void gemm_bt(
    const unsigned short* __restrict__ A, const unsigned short* __restrict__ Bw,
    int M, int N, int K,
    unsigned short* __restrict__ outb,
    unsigned short* __restrict__ koutb, unsigned short* __restrict__ vtout,
    float* __restrict__ outf, const float* __restrict__ bias) {
    __shared__ unsigned short As[128 * 64];  // unpadded: required by global_load_lds
    __shared__ unsigned short Bs[64 * 64];
    const int t = threadIdx.x;
    const int w = t >> 6, lane = t & 63, qd = lane >> 4, c = lane & 15;
    const int m0 = blockIdx.x * 128, n0 = blockIdx.y * 64;
    const int wm = w * 32;

    f32x4 acc[2][4];
    for (int mb = 0; mb < 2; ++mb)
        for (int nb = 0; nb < 4; ++nb) acc[mb][nb] = (f32x4){0.f, 0.f, 0.f, 0.f};

    for (int kk = 0; kk < K; kk += 64) {
        __syncthreads();
#pragma unroll
        for (int is = 0; is < 4; ++is) {
            int vi = is * 256 + t;
            gld16(&A[(size_t)(m0 + (vi >> 3)) * K + kk + (vi & 7) * 8], &As[vi * 8]);
        }
#pragma unroll
        for (int is = 0; is < 2; ++is) {
            int vi = is * 256 + t;
            gld16(&Bw[(size_t)(n0 + (vi >> 3)) * K + kk + (vi & 7) * 8], &Bs[vi * 8]);
        }
        __syncthreads();
#pragma unroll
        for (int kb = 0; kb < 2; ++kb) {
            s16x8 af[2], bf[4];
#pragma unroll
            for (int mb = 0; mb < 2; ++mb)
                af[mb] = *(const s16x8*)&As[(wm + mb * 16 + c) * 64 + kb * 32 + qd * 8];
#pragma unroll
            for (int nb = 0; nb < 4; ++nb)
                bf[nb] = *(const s16x8*)&Bs[(nb * 16 + c) * 64 + kb * 32 + qd * 8];
#pragma unroll
            for (int mb = 0; mb < 2; ++mb)
#pragma unroll
                for (int nb = 0; nb < 4; ++nb)
                    acc[mb][nb] = __builtin_amdgcn_mfma_f32_16x16x32_bf16(af[mb], bf[nb], acc[mb][nb], 0, 0, 0);
        }
    }

#pragma unroll
    for (int mb = 0; mb < 2; ++mb)
#pragma unroll
        for (int nb = 0; nb < 4; ++nb)
#pragma unroll
            for (int r = 0; r < 4; ++r) {
                int row = m0 + wm + mb * 16 + qd * 4 + r;
                int col = n0 + nb * 16 + c;
                float v = acc[mb][nb][r];
                if (MODE == 2) {
                    outf[(size_t)row * 1024 + col] = v + bias[col];
                } else {
                    if (col < 1024)
                        outb[(size_t)row * 1024 + col] = f2b(v);
                    else if (col < 1088)
                        koutb[(size_t)row * 64 + (col - 1024)] = f2b(v);
                    else
                        vtout[(size_t)(row >> 10) * 65536 + (size_t)(col - 1088) * 1024 + (row & 1023)] = f2b(v);
                }
            }
}

// ---------------- fused attention, 4-way j-split flash partials -------------
// grid (i=1024, chunk=4); block 256; wave w = batch b; each block: 2 j-tiles of 128.
__global__ __launch_bounds__(256, 3) void attn_kernel(
    const unsigned short* __restrict__ qb, const unsigned short* __restrict__ kg,
    const unsigned short* __restrict__ vt, const float* __restrict__ rel,
    unsigned short* __restrict__ Opart, float* __restrict__ ml) {
    __shared__ unsigned short rel_s[128 * 72];   // bf16 [128 j][64 d], +8 pad
    __shared__ unsigned short P_s[4 * 16 * 136]; // per-wave [16 h][128 j], +8 pad
    const int i = blockIdx.x;
    const int chunk = blockIdx.y;
    const int t = threadIdx.x;
    const int w = t >> 6, lane = t & 63, qd = lane >> 4, c = lane & 15;
    const int b = w;

    s16x8 aq[2];
    {
        const size_t qbase = ((size_t)(b * S_LEN + i)) * DM + (size_t)c * DH + qd * 8;
        aq[0] = *(const s16x8*)&qb[qbase];
        aq[1] = *(const s16x8*)&qb[qbase + 32];
    }

    f32x4 oacc[4];
    for (int nb = 0; nb < 4; ++nb) oacc[nb] = (f32x4){0.f, 0.f, 0.f, 0.f};
    float m_run[4], l_run[4];
    for (int r = 0; r < 4; ++r) { m_run[r] = -INFINITY; l_run[r] = 0.f; }

    const float C2 = 0.125f * 1.44269504088896f;  // scale * log2(e)

    // prefetch tile 0 rel into registers (flat: rel[(i*1024+chunk*256)*64 + vi*4 ..])
    const size_t rbase = ((size_t)i * S_LEN + chunk * 256) * DH;
    float4 pre[8];
#pragma unroll
    for (int it = 0; it < 8; ++it)
        pre[it] = *(const float4*)&rel[rbase + (size_t)(it * 256 + t) * 4];

#pragma unroll
    for (int jt = 0; jt < 2; ++jt) {
        const int j0 = chunk * 256 + jt * 128;
        __syncthreads();  // previous tile's rel_s readers done
#pragma unroll
        for (int it = 0; it < 8; ++it) {
            int vi = it * 256 + t;
            float4 f = pre[it];
            s16x4 o = { (short)f2b(f.x), (short)f2b(f.y), (short)f2b(f.z), (short)f2b(f.w) };
            *(s16x4*)&rel_s[(vi >> 4) * 72 + (vi & 15) * 4] = o;
        }
        __syncthreads();  // rel_s visible
        if (jt == 0) {
            // prefetch tile 1: in flight through this tile's compute
#pragma unroll
            for (int it = 0; it < 8; ++it)
                pre[it] = *(const float4*)&rel[rbase + 128 * 64 + (size_t)(it * 256 + t) * 4];
        }

        // scores [16 h, 128 j] = Q @ (K + rel)^T, loads hoisted ahead of MFMAs
        f32x4 sa[8];
#pragma unroll
        for (int jb = 0; jb < 8; ++jb) sa[jb] = (f32x4){0.f, 0.f, 0.f, 0.f};
#pragma unroll
        for (int kb = 0; kb < 2; ++kb) {
            s16x8 kf[8], rf[8];
#pragma unroll
            for (int jb = 0; jb < 8; ++jb)
                kf[jb] = *(const s16x8*)&kg[((size_t)b * S_LEN + j0 + jb * 16 + c) * DH + kb * 32 + qd * 8];
#pragma unroll
            for (int jb = 0; jb < 8; ++jb)
                rf[jb] = *(const s16x8*)&rel_s[(jb * 16 + c) * 72 + kb * 32 + qd * 8];
#pragma unroll
            for (int jb = 0; jb < 8; ++jb) {
                sa[jb] = __builtin_amdgcn_mfma_f32_16x16x32_bf16(aq[kb], rf[jb], sa[jb], 0, 0, 0);
                sa[jb] = __builtin_amdgcn_mfma_f32_16x16x32_bf16(aq[kb], kf[jb], sa[jb], 0, 0, 0);
            }
        }

        // online softmax (base-2); C-layout row h = qd*4+r, col j = jb*16+c
        float alpha[4];
#pragma unroll
        for (int r = 0; r < 4; ++r) {
            float mx = -INFINITY;
#pragma unroll
            for (int jb = 0; jb < 8; ++jb) {
                sa[jb][r] *= C2;
                mx = fmaxf(mx, sa[jb][r]);
            }
            mx = fmaxf(mx, __shfl_xor(mx, 1));
            mx = fmaxf(mx, __shfl_xor(mx, 2));
            mx = fmaxf(mx, __shfl_xor(mx, 4));
            mx = fmaxf(mx, __shfl_xor(mx, 8));
            float mnew = fmaxf(m_run[r], mx);
            alpha[r] = exp2f(m_run[r] - mnew);
            m_run[r] = mnew;
            float s = 0.f;
#pragma unroll
            for (int jb = 0; jb < 8; ++jb) {
                float p = exp2f(sa[jb][r] - mnew);
                s += p;
                P_s[(w * 16 + qd * 4 + r) * 136 + jb * 16 + c] = f2b(p);
            }
            s += __shfl_xor(s, 1);
            s += __shfl_xor(s, 2);
            s += __shfl_xor(s, 4);
            s += __shfl_xor(s, 8);
            l_run[r] = l_run[r] * alpha[r] + s;
        }
#pragma unroll
        for (int nb = 0; nb < 4; ++nb)
#pragma unroll
            for (int r = 0; r < 4; ++r) oacc[nb][r] *= alpha[r];

        // NO barrier: P_s rows are wave-private; compiler emits the lgkmcnt wait.
        // PV: O[16,64] += P[16,128] @ V[128,64] (V^T rows are contiguous bf16)
#pragma unroll
        for (int kk2 = 0; kk2 < 4; ++kk2) {
            s16x8 vf[4];
#pragma unroll
            for (int nb = 0; nb < 4; ++nb)
                vf[nb] = *(const s16x8*)&vt[(size_t)b * 65536 + (size_t)(nb * 16 + c) * 1024 + j0 + kk2 * 32 + qd * 8];
            s16x8 pf = *(const s16x8*)&P_s[(w * 16 + c) * 136 + kk2 * 32 + qd * 8];
#pragma unroll
            for (int nb = 0; nb < 4; ++nb)
                oacc[nb] = __builtin_amdgcn_mfma_f32_16x16x32_bf16(pf, vf[nb], oacc[nb], 0, 0, 0);
        }
    }

    // epilogue: un-normalized partials (bf16) + m,l (fp32)
#pragma unroll
    for (int nb = 0; nb < 4; ++nb)
#pragma unroll
        for (int r = 0; r < 4; ++r)
            Opart[((size_t)chunk * S_LEN + i) * 4096 + b * 1024 + (qd * 4 + r) * 64 + nb * 16 + c] =
                f2b(oacc[nb][r]);
    if (c == 0) {
#pragma unroll
        for (int r = 0; r < 4; ++r) {
            size_t base = (((size_t)chunk * S_LEN + i) * 64 + b * 16 + qd * 4 + r) * 2;
            ml[base] = m_run[r];
            ml[base + 1] = l_run[r];
        }
    }
}

// ---------------- merge 4 chunk-partials -> ctx bf16 -----------------------
__global__ __launch_bounds__(256) void merge_kernel(
    const unsigned short* __restrict__ Opart, const float* __restrict__ ml,
    unsigned short* __restrict__ ctx) {
    const int i = blockIdx.x, t = threadIdx.x;
#pragma unroll
    for (int k = 0; k < 4; ++k) {
        int e = k * 1024 + t * 4;  // flat b*1024 + h*64 + d
        int bh = e >> 6;           // b*16 + h
        float m_c[4], l_c[4];
#pragma unroll
        for (int cc = 0; cc < 4; ++cc) {
            size_t base = (((size_t)cc * S_LEN + i) * 64 + bh) * 2;
            m_c[cc] = ml[base];
            l_c[cc] = ml[base + 1];
        }
        float mstar = fmaxf(fmaxf(m_c[0], m_c[1]), fmaxf(m_c[2], m_c[3]));
        float o0 = 0.f, o1 = 0.f, o2 = 0.f, o3 = 0.f, lsum = 0.f;
#pragma unroll
        for (int cc = 0; cc < 4; ++cc) {
            float wgt = exp2f(m_c[cc] - mstar);
            lsum += l_c[cc] * wgt;
            s16x4 ov = *(const s16x4*)&Opart[((size_t)cc * S_LEN + i) * 4096 + e];
            o0 += b2f((unsigned short)ov[0]) * wgt;
            o1 += b2f((unsigned short)ov[1]) * wgt;
            o2 += b2f((unsigned short)ov[2]) * wgt;
            o3 += b2f((unsigned short)ov[3]) * wgt;
        }
        float inv = 1.0f / lsum;
        s16x4 o = { (short)f2b(o0 * inv), (short)f2b(o1 * inv),
                    (short)f2b(o2 * inv), (short)f2b(o3 * inv) };
        *(s16x4*)&ctx[((size_t)(e >> 10) * S_LEN + i) * 1024 + (e & 1023)] = o;
    }
}

extern "C" void kernel_launch(void* const* d_in, const int* in_sizes, int n_in,
                              void* d_out, int out_size, void* d_ws, size_t ws_size,
                              hipStream_t stream) {
    (void)in_sizes; (void)n_in; (void)out_size; (void)ws_size;
    const float* x   = (const float*)d_in[0];
    const float* rel = (const float*)d_in[1];
    const float* Wq  = (const float*)d_in[2];
    const float* Wk  = (const float*)d_in[3];
    const float* Wv  = (const float*)d_in[4];
    const float* Wo  = (const float*)d_in[5];
    const float* bo  = (const float*)d_in[6];
    float* out = (float*)d_out;

    unsigned short* ws  = (unsigned short*)d_ws;
    unsigned short* xb   = ws;              // 4M
    unsigned short* wqb  = xb + 4194304;    // 1M   (wq, wk, wv contiguous -> N=1152 fused B)
    unsigned short* wkb  = wqb + 1048576;   // 64K
    unsigned short* wvb  = wkb + 65536;     // 64K
    unsigned short* wob  = wvb + 65536;     // 1M
    unsigned short* qbf  = wob + 1048576;   // 4M
    unsigned short* kbf  = qbf + 4194304;   // [4][1024][64]
    unsigned short* vtb  = kbf + 262144;    // [4][64][1024]
    unsigned short* ctxb = vtb + 262144;    // 4M
    unsigned short* Opart = ctxb + 4194304; // [4][1024][4096] bf16 = 33.5 MB
    float* mlf = (float*)(Opart + 16777216); // [4][1024][64][2] fp32 = 2 MB

    convert_all<<<1024, 256, 0, stream>>>(x, Wq, Wk, Wv, Wo, xb, wqb, wkb, wvb, wob);
    // fused Q/K/V projection: B = [Wq; Wk; Wv] rows 0..1151
    gemm_bt<0><<<dim3(32, 18), 256, 0, stream>>>(xb, wqb, 4096, 1152, 1024,
                                                 qbf, kbf, vtb, nullptr, nullptr);
    attn_kernel<<<dim3(1024, 4), 256, 0, stream>>>(qbf, kbf, vtb, rel, Opart, mlf);
    merge_kernel<<<1024, 256, 0, stream>>>(Opart, mlf, ctxb);
    gemm_bt<2><<<dim3(32, 16), 256, 0, stream>>>(ctxb, wob, 4096, 1024, 1024,
                                                 nullptr, nullptr, nullptr, out, bo);
}